// Round 18
// baseline (115.015 us; speedup 1.0000x reference)
//
#include <hip/hip_runtime.h>

// Problem constants
#define BB 4
#define SS 2048
#define DM 256
#define NH 4
#define DH 64
#define NROW (BB*SS)              // 8192
#define NE   (3*DM)               // 768
#define BH   (BB*NH)              // 16
#define HEAD_ELEMS (BH*SS*DH)     // 2097152 per tensor
#define NQROWS (BH*SS)            // 32768
#define NKZ 4                     // split-K ways in attn

typedef _Float16 half_t;
typedef __attribute__((ext_vector_type(8))) _Float16 half8;
typedef __attribute__((ext_vector_type(4))) _Float16 half4;
typedef __attribute__((ext_vector_type(4))) float floatx4;

#define KPAD 72                   // LDS stride (halfs), 16B-aligned rows

// exp2-domain softmax: scores are pre-scaled by 1/sqrt(64) * log2(e)
#define QK_SCALE 0.18033688011112042f
#define EXP2(x) __builtin_amdgcn_exp2f(x)
#define DEFER_THR 8.0f            // skip O-rescale while max grows < 8 (log2 units)

// ---------------------------------------------------------------------------
// QKV projection (B-stationary), fp16 MFMA. BOTH x and W are read as fp32
// and converted fp32->fp16 in-flight during staging (no prep dispatch;
// identical rounding, absmax unchanged). Single-precision x: error budget
// has ~2x headroom (absmax 9.77e-4 vs 2.77e-3 threshold).
// Epilogue: q scaled by 1/8*log2e; k scatter; v transposed through LDS.
// ---------------------------------------------------------------------------
__global__ __launch_bounds__(256) void qkv_proj(const float* __restrict__ x,
                                                const float* __restrict__ Wg,
                                                const float* __restrict__ bias,
                                                half_t* __restrict__ qh,
                                                half_t* __restrict__ kh,
                                                half_t* __restrict__ vt) {
    __shared__ __align__(16) half_t Xh[64 * KPAD];
    __shared__ __align__(16) half_t Wh[64 * KPAD];

    const int rb   = blockIdx.x * 64;
    const int nb   = blockIdx.y * 64;
    const int tid  = threadIdx.x;
    const int wid  = tid >> 6;
    const int lane = tid & 63;
    const int quad = lane >> 4;
    const int col  = lane & 15;

    floatx4 acc[4];
    #pragma unroll
    for (int t = 0; t < 4; ++t) acc[t] = (floatx4){0.f, 0.f, 0.f, 0.f};

    for (int k0 = 0; k0 < DM; k0 += 64) {
        __syncthreads();
        #pragma unroll
        for (int i = 0; i < 2; ++i) {
            int gi = tid + 256 * i;        // 0..511
            int r  = gi >> 3;              // 0..63
            int c8 = (gi & 7) * 8;         // 0..56
            const float* xp = &x[(size_t)(rb + r) * DM + k0 + c8];
            float4 v0 = *(const float4*)xp;
            float4 v1 = *(const float4*)(xp + 4);
            half8 h;
            h[0] = (half_t)v0.x; h[1] = (half_t)v0.y;
            h[2] = (half_t)v0.z; h[3] = (half_t)v0.w;
            h[4] = (half_t)v1.x; h[5] = (half_t)v1.y;
            h[6] = (half_t)v1.z; h[7] = (half_t)v1.w;
            *(half8*)&Xh[r * KPAD + c8] = h;

            const float* wp = &Wg[(size_t)(nb + r) * DM + k0 + c8];
            float4 w0 = *(const float4*)wp;
            float4 w1 = *(const float4*)(wp + 4);
            half8 wv;
            wv[0] = (half_t)w0.x; wv[1] = (half_t)w0.y;
            wv[2] = (half_t)w0.z; wv[3] = (half_t)w0.w;
            wv[4] = (half_t)w1.x; wv[5] = (half_t)w1.y;
            wv[6] = (half_t)w1.z; wv[7] = (half_t)w1.w;
            *(half8*)&Wh[r * KPAD + c8] = wv;
        }
        __syncthreads();

        half8 ah0 = *(const half8*)&Xh[(wid * 16 + col) * KPAD + quad * 8];
        half8 ah1 = *(const half8*)&Xh[(wid * 16 + col) * KPAD + 32 + quad * 8];

        #pragma unroll
        for (int t = 0; t < 4; ++t) {
            half8 bh0 = *(const half8*)&Wh[(t * 16 + col) * KPAD + quad * 8];
            half8 bh1 = *(const half8*)&Wh[(t * 16 + col) * KPAD + 32 + quad * 8];
            acc[t] = __builtin_amdgcn_mfma_f32_16x16x32_f16(ah0, bh0, acc[t], 0, 0, 0);
            acc[t] = __builtin_amdgcn_mfma_f32_16x16x32_f16(ah1, bh1, acc[t], 0, 0, 0);
        }
    }

    const int part = nb >> 8;           // block-uniform: 0=q 1=k 2=v
    const int mloc = wid * 16 + quad * 4;
    if (part != 2) {
        #pragma unroll
        for (int t = 0; t < 4; ++t) {
            int e    = nb + t * 16 + col;
            float be = bias[e];
            int dm   = e & 255;
            int h    = dm >> 6;
            int dh   = dm & 63;
            #pragma unroll
            for (int r = 0; r < 4; ++r) {
                int row = rb + mloc + r;
                int b   = row >> 11;
                int s   = row & 2047;
                int bh_ = b * NH + h;
                float val = acc[t][r] + be;
                if (part == 0) {
                    qh[((size_t)bh_ * SS + s) * DH + dh] = (half_t)(val * QK_SCALE);
                } else {
                    kh[((size_t)bh_ * SS + s) * DH + dh] = (half_t)val;
                }
            }
        }
    } else {
        __syncthreads();
        #pragma unroll
        for (int t = 0; t < 4; ++t) {
            int e    = nb + t * 16 + col;
            float be = bias[e];
            #pragma unroll
            for (int r = 0; r < 4; ++r)
                Xh[(t * 16 + col) * KPAD + mloc + r] = (half_t)(acc[t][r] + be);
        }
        __syncthreads();
        const int b   = rb >> 11;
        const int s0  = rb & 2047;
        const int h   = (nb >> 6) & 3;
        const int bh_ = b * NH + h;
        #pragma unroll
        for (int i = 0; i < 2; ++i) {
            int idx = tid + 256 * i;
            int rr  = idx >> 3;
            int cc8 = (idx & 7) * 8;
            *(half8*)&vt[((size_t)bh_ * DH + rr) * SS + s0 + cc8] =
                *(const half8*)&Xh[rr * KPAD + cc8];
        }
    }
}

// ---------------------------------------------------------------------------
// Flash attention (R9/R13/R15 exact: dual-strip, split-K(4), KVBLK=64,
// deferred-l, exp2-domain, defer-max, XCD stream remap). UNTOUCHED.
// ---------------------------------------------------------------------------
__global__ __launch_bounds__(256) void attn(const half_t* __restrict__ qh,
                                            const half_t* __restrict__ kh,
                                            const half_t* __restrict__ vt,
                                            half_t* __restrict__ pO,
                                            float* __restrict__ mst,
                                            float* __restrict__ lst) {
    __shared__ __align__(16) half_t Ks[64 * KPAD];    // 9.2 KB
    __shared__ __align__(16) half_t Vts[64 * KPAD];   // 9.2 KB

    // XCD stream-affinity remap (bijective over 1024 blocks).
    const int lin  = blockIdx.x + 16 * blockIdx.y + 256 * blockIdx.z;  // 0..1023
    const int xcd  = lin & 7;
    const int j    = lin >> 3;                  // 0..127
    const int strm = xcd + 8 * (j >> 4);        // 0..63
    const int q0   = (j & 15) * 128;
    const int bh   = strm & 15;
    const int kz   = strm >> 4;                 // 0..3

    const size_t base = (size_t)bh * SS * DH;
    const int tid  = threadIdx.x;
    const int wid  = tid >> 6;    // 0..3
    const int lane = tid & 63;
    const int quad = lane >> 4;
    const int col  = lane & 15;
    const int ktBeg = kz * (SS / NKZ);
    const int ktEnd = ktBeg + (SS / NKZ);       // 512-wide k range, 8 tiles

    int srr[2], scc[2];
    #pragma unroll
    for (int i = 0; i < 2; ++i) {
        int gi = tid + 256 * i;    // 0..511
        srr[i] = gi >> 3;          // 0..63
        scc[i] = (gi & 7) * 8;     // 0..56
    }

    // Q B-frags: 2 strips of 16 q rows per wave (pre-scaled by 0.125*log2e)
    half8 bq[2][2];
    #pragma unroll
    for (int st = 0; st < 2; ++st) {
        int s = q0 + wid * 32 + st * 16 + col;
        bq[st][0] = *(const half8*)&qh[base + (size_t)s * DH + quad * 8];
        bq[st][1] = *(const half8*)&qh[base + (size_t)s * DH + 32 + quad * 8];
    }

    // Preload tile ktBeg
    half8 nk[2], nv[2];
    #pragma unroll
    for (int i = 0; i < 2; ++i) {
        nk[i] = *(const half8*)&kh[base + (size_t)(ktBeg + srr[i]) * DH + scc[i]];
        nv[i] = *(const half8*)&vt[base + (size_t)srr[i] * SS + ktBeg + scc[i]];
    }

    float m_i[2]    = {-3.0e38f, -3.0e38f};
    float l_part[2] = {0.f, 0.f};     // per-lane partials (deferred reduction)
    floatx4 o[2][4];
    #pragma unroll
    for (int st = 0; st < 2; ++st)
        #pragma unroll
        for (int dt = 0; dt < 4; ++dt) o[st][dt] = (floatx4){0.f, 0.f, 0.f, 0.f};

    for (int kt = ktBeg; kt < ktEnd; kt += 64) {
        __syncthreads();
        #pragma unroll
        for (int i = 0; i < 2; ++i) {
            *(half8*)&Ks[srr[i] * KPAD + scc[i]]  = nk[i];
            *(half8*)&Vts[srr[i] * KPAD + scc[i]] = nv[i];
        }
        __syncthreads();

        // Prefetch next tile (in flight across compute)
        const int ktn = kt + 64;
        if (ktn < ktEnd) {
            #pragma unroll
            for (int i = 0; i < 2; ++i) {
                nk[i] = *(const half8*)&kh[base + (size_t)(ktn + srr[i]) * DH + scc[i]];
                nv[i] = *(const half8*)&vt[base + (size_t)srr[i] * SS + ktn + scc[i]];
            }
        }

        // S^T = K . Q^T for both strips (ak frags shared: 1 read, 2 MFMAs)
        floatx4 sc[2][4];
        #pragma unroll
        for (int t = 0; t < 4; ++t) {
            half8 ak0 = *(const half8*)&Ks[(t * 16 + col) * KPAD + quad * 8];
            half8 ak1 = *(const half8*)&Ks[(t * 16 + col) * KPAD + 32 + quad * 8];
            #pragma unroll
            for (int st = 0; st < 2; ++st) {
                floatx4 c = (floatx4){0.f, 0.f, 0.f, 0.f};
                c = __builtin_amdgcn_mfma_f32_16x16x32_f16(ak0, bq[st][0], c, 0, 0, 0);
                c = __builtin_amdgcn_mfma_f32_16x16x32_f16(ak1, bq[st][1], c, 0, 0, 0);
                sc[st][t] = c;
            }
        }

        // Online softmax per strip (exp2 domain, defer-max, deferred-l)
        half4 pa[2][4];
        #pragma unroll
        for (int st = 0; st < 2; ++st) {
            float mloc = -3.0e38f;
            #pragma unroll
            for (int t = 0; t < 4; ++t) {
                float a = fmaxf(fmaxf(sc[st][t][0], sc[st][t][1]),
                                fmaxf(sc[st][t][2], sc[st][t][3]));
                mloc = fmaxf(mloc, a);
            }
            mloc = fmaxf(mloc, __shfl_xor(mloc, 16));
            mloc = fmaxf(mloc, __shfl_xor(mloc, 32));

            bool skip = __all(mloc <= m_i[st] + DEFER_THR);
            float m_new = skip ? m_i[st] : fmaxf(m_i[st], mloc);

            float rsumL = 0.f;
            #pragma unroll
            for (int t = 0; t < 4; ++t) {
                float p0 = EXP2(sc[st][t][0] - m_new);
                float p1 = EXP2(sc[st][t][1] - m_new);
                float p2 = EXP2(sc[st][t][2] - m_new);
                float p3 = EXP2(sc[st][t][3] - m_new);
                rsumL += p0 + p1 + p2 + p3;
                pa[st][t] = (half4){(half_t)p0, (half_t)p1, (half_t)p2, (half_t)p3};
            }

            if (skip) {
                l_part[st] += rsumL;
            } else {
                float alpha = EXP2(m_i[st] - m_new);
                m_i[st] = m_new;
                l_part[st] = l_part[st] * alpha + rsumL;
                float ar[4];
                #pragma unroll
                for (int i = 0; i < 4; ++i) ar[i] = __shfl(alpha, quad * 4 + i);
                #pragma unroll
                for (int dt = 0; dt < 4; ++dt)
                    #pragma unroll
                    for (int i = 0; i < 4; ++i)
                        o[st][dt][i] *= ar[i];
            }
        }

        // O += P . V (bv frags shared: 1 read, 2 MFMAs)
        #pragma unroll
        for (int t = 0; t < 4; ++t) {
            #pragma unroll
            for (int dt = 0; dt < 4; ++dt) {
                half4 bv = *(const half4*)&Vts[(dt * 16 + col) * KPAD + t * 16 + quad * 4];
                #pragma unroll
                for (int st = 0; st < 2; ++st)
                    o[st][dt] = __builtin_amdgcn_mfma_f32_16x16x16f16(pa[st][t], bv, o[st][dt], 0, 0, 0);
            }
        }
    }

    // Epilogue: one cross-lane l reduction per strip; normalized partial O.
    const size_t pbase = (size_t)kz * HEAD_ELEMS + base;
    #pragma unroll
    for (int st = 0; st < 2; ++st) {
        float l_i = l_part[st] + __shfl_xor(l_part[st], 16);
        l_i += __shfl_xor(l_i, 32);
        float inv = 1.0f / l_i;
        float ir[4];
        #pragma unroll
        for (int i = 0; i < 4; ++i) ir[i] = __shfl(inv, quad * 4 + i);
        #pragma unroll
        for (int dt = 0; dt < 4; ++dt)
            #pragma unroll
            for (int i = 0; i < 4; ++i) {
                int row = q0 + wid * 32 + st * 16 + quad * 4 + i;
                pO[pbase + (size_t)row * DH + dt * 16 + col] = (half_t)(o[st][dt][i] * ir[i]);
            }
        if (quad == 0) {
            int row = q0 + wid * 32 + st * 16 + col;
            int idx = kz * NQROWS + bh * SS + row;
            mst[idx] = m_i[st];
            lst[idx] = l_i;
        }
    }
}

// ---------------------------------------------------------------------------
// merge: combine the four kz partials (m stats are log2-domain).
// 512 blocks x 256 thr, 16 d-elems per thread: stats redundancy 8x -> 4x,
// half the blocks. Identical arithmetic to the 8-elem version.
// ---------------------------------------------------------------------------
__global__ __launch_bounds__(256) void merge(const half_t* __restrict__ pO,
                                             const float* __restrict__ mst,
                                             const float* __restrict__ lst,
                                             float* __restrict__ out) {
    int gid = blockIdx.x * 256 + threadIdx.x;   // 0..131071
    int row = gid >> 2;                         // 0..32767 (bh*SS + s)
    int dc  = (gid & 3) * 16;
    float m[NKZ], l[NKZ];
    #pragma unroll
    for (int p = 0; p < NKZ; ++p) {
        m[p] = mst[p * NQROWS + row];
        l[p] = lst[p * NQROWS + row];
    }
    float M = fmaxf(fmaxf(m[0], m[1]), fmaxf(m[2], m[3]));
    float w[NKZ], wsum = 0.f;
    #pragma unroll
    for (int p = 0; p < NKZ; ++p) { w[p] = l[p] * EXP2(m[p] - M); wsum += w[p]; }
    float inv = 1.0f / wsum;

    float r[16];
    #pragma unroll
    for (int e = 0; e < 16; ++e) r[e] = 0.f;
    #pragma unroll
    for (int p = 0; p < NKZ; ++p) {
        float a = w[p] * inv;
        const half_t* pp = &pO[(size_t)p * HEAD_ELEMS + (size_t)row * DH + dc];
        half8 o1 = *(const half8*)pp;
        half8 o2 = *(const half8*)(pp + 8);
        #pragma unroll
        for (int e = 0; e < 8; ++e) { r[e] += a * (float)o1[e]; r[8 + e] += a * (float)o2[e]; }
    }
    #pragma unroll
    for (int q = 0; q < 4; ++q) {
        float4 rv = {r[q * 4], r[q * 4 + 1], r[q * 4 + 2], r[q * 4 + 3]};
        *(float4*)&out[(size_t)row * DH + dc + q * 4] = rv;
    }
}

extern "C" void kernel_launch(void* const* d_in, const int* in_sizes, int n_in,
                              void* d_out, int out_size, void* d_ws, size_t ws_size,
                              hipStream_t stream) {
    const float* x  = (const float*)d_in[0];   // [4,2048,256]
    const float* Wq = (const float*)d_in[1];   // [768,256]
    const float* bq = (const float*)d_in[2];   // [768]
    float* out = (float*)d_out;                // [4,4,2048,64]

    // ws layout (units of HEAD_ELEMS halfs; HE = 2M halfs = 4 MB):
    //   qh 0 | kh 1 | vt 2 | (3,4,5 free)
    //   pO 6..10 (4 kz partials, 16 MB) | stats f32 at byte 10*HE*2 (~42 MB)
    //   total ~43 MB; ws_size is 256 MiB.
    half_t* qh  = (half_t*)d_ws;
    half_t* kh  = qh + (size_t)HEAD_ELEMS;
    half_t* vt  = kh + (size_t)HEAD_ELEMS;
    half_t* pO  = (half_t*)d_ws + (size_t)6 * HEAD_ELEMS;  // 4 x HE halfs
    float*  mst = (float*)((char*)d_ws + (size_t)10 * HEAD_ELEMS * 2);
    float*  lst = mst + (size_t)NKZ * NQROWS;

    qkv_proj<<<dim3(NROW / 64, NE / 64), 256, 0, stream>>>(x, Wq, bq, qh, kh, vt);
    attn<<<dim3(SS / 128, BH, NKZ), 256, 0, stream>>>(qh, kh, vt, pO, mst, lst);
    merge<<<512, 256, 0, stream>>>(pO, mst, lst, out);
}

// Round 19
// 108.924 us; speedup vs baseline: 1.0559x; 1.0559x over previous
//
#include <hip/hip_runtime.h>

// Problem constants
#define BB 4
#define SS 2048
#define DM 256
#define NH 4
#define DH 64
#define NROW (BB*SS)              // 8192
#define NE   (3*DM)               // 768
#define BH   (BB*NH)              // 16
#define HEAD_ELEMS (BH*SS*DH)     // 2097152 per tensor
#define NQROWS (BH*SS)            // 32768
#define NKZ 4                     // split-K ways in attn

typedef _Float16 half_t;
typedef __attribute__((ext_vector_type(8))) _Float16 half8;
typedef __attribute__((ext_vector_type(4))) _Float16 half4;
typedef __attribute__((ext_vector_type(4))) float floatx4;

#define KPAD 72                   // LDS stride (halfs), 16B-aligned rows

// exp2-domain softmax: scores are pre-scaled by 1/sqrt(64) * log2(e)
#define QK_SCALE 0.18033688011112042f
#define EXP2(x) __builtin_amdgcn_exp2f(x)
#define DEFER_THR 8.0f            // skip O-rescale while max grows < 8 (log2 units)

// ---------------------------------------------------------------------------
// QKV projection (B-stationary), fp16 MFMA. BOTH x and W are read as fp32
// and converted fp32->fp16 in-flight during staging -- no prep dispatch.
// Single-precision x: error budget has ~2x headroom (absmax 9.77e-4 vs
// 2.77e-3 threshold; hi/lo split was pure waste -- R13 measured identical
// absmax).
// Epilogue: q scaled by 1/8*log2e; k scatter; v transposed through LDS.
// ---------------------------------------------------------------------------
__global__ __launch_bounds__(256) void qkv_proj(const float* __restrict__ x,
                                                const float* __restrict__ Wg,
                                                const float* __restrict__ bias,
                                                half_t* __restrict__ qh,
                                                half_t* __restrict__ kh,
                                                half_t* __restrict__ vt) {
    __shared__ __align__(16) half_t Xh[64 * KPAD];
    __shared__ __align__(16) half_t Wh[64 * KPAD];

    const int rb   = blockIdx.x * 64;
    const int nb   = blockIdx.y * 64;
    const int tid  = threadIdx.x;
    const int wid  = tid >> 6;
    const int lane = tid & 63;
    const int quad = lane >> 4;
    const int col  = lane & 15;

    floatx4 acc[4];
    #pragma unroll
    for (int t = 0; t < 4; ++t) acc[t] = (floatx4){0.f, 0.f, 0.f, 0.f};

    for (int k0 = 0; k0 < DM; k0 += 64) {
        __syncthreads();
        #pragma unroll
        for (int i = 0; i < 2; ++i) {
            int gi = tid + 256 * i;        // 0..511
            int r  = gi >> 3;              // 0..63
            int c8 = (gi & 7) * 8;         // 0..56
            const float* xp = &x[(size_t)(rb + r) * DM + k0 + c8];
            float4 v0 = *(const float4*)xp;
            float4 v1 = *(const float4*)(xp + 4);
            half8 h;
            h[0] = (half_t)v0.x; h[1] = (half_t)v0.y;
            h[2] = (half_t)v0.z; h[3] = (half_t)v0.w;
            h[4] = (half_t)v1.x; h[5] = (half_t)v1.y;
            h[6] = (half_t)v1.z; h[7] = (half_t)v1.w;
            *(half8*)&Xh[r * KPAD + c8] = h;

            const float* wp = &Wg[(size_t)(nb + r) * DM + k0 + c8];
            float4 w0 = *(const float4*)wp;
            float4 w1 = *(const float4*)(wp + 4);
            half8 wv;
            wv[0] = (half_t)w0.x; wv[1] = (half_t)w0.y;
            wv[2] = (half_t)w0.z; wv[3] = (half_t)w0.w;
            wv[4] = (half_t)w1.x; wv[5] = (half_t)w1.y;
            wv[6] = (half_t)w1.z; wv[7] = (half_t)w1.w;
            *(half8*)&Wh[r * KPAD + c8] = wv;
        }
        __syncthreads();

        half8 ah0 = *(const half8*)&Xh[(wid * 16 + col) * KPAD + quad * 8];
        half8 ah1 = *(const half8*)&Xh[(wid * 16 + col) * KPAD + 32 + quad * 8];

        #pragma unroll
        for (int t = 0; t < 4; ++t) {
            half8 bh0 = *(const half8*)&Wh[(t * 16 + col) * KPAD + quad * 8];
            half8 bh1 = *(const half8*)&Wh[(t * 16 + col) * KPAD + 32 + quad * 8];
            acc[t] = __builtin_amdgcn_mfma_f32_16x16x32_f16(ah0, bh0, acc[t], 0, 0, 0);
            acc[t] = __builtin_amdgcn_mfma_f32_16x16x32_f16(ah1, bh1, acc[t], 0, 0, 0);
        }
    }

    const int part = nb >> 8;           // block-uniform: 0=q 1=k 2=v
    const int mloc = wid * 16 + quad * 4;
    if (part != 2) {
        #pragma unroll
        for (int t = 0; t < 4; ++t) {
            int e    = nb + t * 16 + col;
            float be = bias[e];
            int dm   = e & 255;
            int h    = dm >> 6;
            int dh   = dm & 63;
            #pragma unroll
            for (int r = 0; r < 4; ++r) {
                int row = rb + mloc + r;
                int b   = row >> 11;
                int s   = row & 2047;
                int bh_ = b * NH + h;
                float val = acc[t][r] + be;
                if (part == 0) {
                    qh[((size_t)bh_ * SS + s) * DH + dh] = (half_t)(val * QK_SCALE);
                } else {
                    kh[((size_t)bh_ * SS + s) * DH + dh] = (half_t)val;
                }
            }
        }
    } else {
        __syncthreads();
        #pragma unroll
        for (int t = 0; t < 4; ++t) {
            int e    = nb + t * 16 + col;
            float be = bias[e];
            #pragma unroll
            for (int r = 0; r < 4; ++r)
                Xh[(t * 16 + col) * KPAD + mloc + r] = (half_t)(acc[t][r] + be);
        }
        __syncthreads();
        const int b   = rb >> 11;
        const int s0  = rb & 2047;
        const int h   = (nb >> 6) & 3;
        const int bh_ = b * NH + h;
        #pragma unroll
        for (int i = 0; i < 2; ++i) {
            int idx = tid + 256 * i;
            int rr  = idx >> 3;
            int cc8 = (idx & 7) * 8;
            *(half8*)&vt[((size_t)bh_ * DH + rr) * SS + s0 + cc8] =
                *(const half8*)&Xh[rr * KPAD + cc8];
        }
    }
}

// ---------------------------------------------------------------------------
// Flash attention (dual-strip, split-K(4), KVBLK=64, deferred-l,
// exp2-domain, defer-max, XCD stream remap). Best-measured configuration
// (109.4/109.5 us in two independent builds).
// ---------------------------------------------------------------------------
__global__ __launch_bounds__(256) void attn(const half_t* __restrict__ qh,
                                            const half_t* __restrict__ kh,
                                            const half_t* __restrict__ vt,
                                            half_t* __restrict__ pO,
                                            float* __restrict__ mst,
                                            float* __restrict__ lst) {
    __shared__ __align__(16) half_t Ks[64 * KPAD];    // 9.2 KB
    __shared__ __align__(16) half_t Vts[64 * KPAD];   // 9.2 KB

    // XCD stream-affinity remap (bijective over 1024 blocks).
    const int lin  = blockIdx.x + 16 * blockIdx.y + 256 * blockIdx.z;  // 0..1023
    const int xcd  = lin & 7;
    const int j    = lin >> 3;                  // 0..127
    const int strm = xcd + 8 * (j >> 4);        // 0..63
    const int q0   = (j & 15) * 128;
    const int bh   = strm & 15;
    const int kz   = strm >> 4;                 // 0..3

    const size_t base = (size_t)bh * SS * DH;
    const int tid  = threadIdx.x;
    const int wid  = tid >> 6;    // 0..3
    const int lane = tid & 63;
    const int quad = lane >> 4;
    const int col  = lane & 15;
    const int ktBeg = kz * (SS / NKZ);
    const int ktEnd = ktBeg + (SS / NKZ);       // 512-wide k range, 8 tiles

    int srr[2], scc[2];
    #pragma unroll
    for (int i = 0; i < 2; ++i) {
        int gi = tid + 256 * i;    // 0..511
        srr[i] = gi >> 3;          // 0..63
        scc[i] = (gi & 7) * 8;     // 0..56
    }

    // Q B-frags: 2 strips of 16 q rows per wave (pre-scaled by 0.125*log2e)
    half8 bq[2][2];
    #pragma unroll
    for (int st = 0; st < 2; ++st) {
        int s = q0 + wid * 32 + st * 16 + col;
        bq[st][0] = *(const half8*)&qh[base + (size_t)s * DH + quad * 8];
        bq[st][1] = *(const half8*)&qh[base + (size_t)s * DH + 32 + quad * 8];
    }

    // Preload tile ktBeg
    half8 nk[2], nv[2];
    #pragma unroll
    for (int i = 0; i < 2; ++i) {
        nk[i] = *(const half8*)&kh[base + (size_t)(ktBeg + srr[i]) * DH + scc[i]];
        nv[i] = *(const half8*)&vt[base + (size_t)srr[i] * SS + ktBeg + scc[i]];
    }

    float m_i[2]    = {-3.0e38f, -3.0e38f};
    float l_part[2] = {0.f, 0.f};     // per-lane partials (deferred reduction)
    floatx4 o[2][4];
    #pragma unroll
    for (int st = 0; st < 2; ++st)
        #pragma unroll
        for (int dt = 0; dt < 4; ++dt) o[st][dt] = (floatx4){0.f, 0.f, 0.f, 0.f};

    for (int kt = ktBeg; kt < ktEnd; kt += 64) {
        __syncthreads();
        #pragma unroll
        for (int i = 0; i < 2; ++i) {
            *(half8*)&Ks[srr[i] * KPAD + scc[i]]  = nk[i];
            *(half8*)&Vts[srr[i] * KPAD + scc[i]] = nv[i];
        }
        __syncthreads();

        // Prefetch next tile (in flight across compute)
        const int ktn = kt + 64;
        if (ktn < ktEnd) {
            #pragma unroll
            for (int i = 0; i < 2; ++i) {
                nk[i] = *(const half8*)&kh[base + (size_t)(ktn + srr[i]) * DH + scc[i]];
                nv[i] = *(const half8*)&vt[base + (size_t)srr[i] * SS + ktn + scc[i]];
            }
        }

        // S^T = K . Q^T for both strips (ak frags shared: 1 read, 2 MFMAs)
        floatx4 sc[2][4];
        #pragma unroll
        for (int t = 0; t < 4; ++t) {
            half8 ak0 = *(const half8*)&Ks[(t * 16 + col) * KPAD + quad * 8];
            half8 ak1 = *(const half8*)&Ks[(t * 16 + col) * KPAD + 32 + quad * 8];
            #pragma unroll
            for (int st = 0; st < 2; ++st) {
                floatx4 c = (floatx4){0.f, 0.f, 0.f, 0.f};
                c = __builtin_amdgcn_mfma_f32_16x16x32_f16(ak0, bq[st][0], c, 0, 0, 0);
                c = __builtin_amdgcn_mfma_f32_16x16x32_f16(ak1, bq[st][1], c, 0, 0, 0);
                sc[st][t] = c;
            }
        }

        // Online softmax per strip (exp2 domain, defer-max, deferred-l)
        half4 pa[2][4];
        #pragma unroll
        for (int st = 0; st < 2; ++st) {
            float mloc = -3.0e38f;
            #pragma unroll
            for (int t = 0; t < 4; ++t) {
                float a = fmaxf(fmaxf(sc[st][t][0], sc[st][t][1]),
                                fmaxf(sc[st][t][2], sc[st][t][3]));
                mloc = fmaxf(mloc, a);
            }
            mloc = fmaxf(mloc, __shfl_xor(mloc, 16));
            mloc = fmaxf(mloc, __shfl_xor(mloc, 32));

            bool skip = __all(mloc <= m_i[st] + DEFER_THR);
            float m_new = skip ? m_i[st] : fmaxf(m_i[st], mloc);

            float rsumL = 0.f;
            #pragma unroll
            for (int t = 0; t < 4; ++t) {
                float p0 = EXP2(sc[st][t][0] - m_new);
                float p1 = EXP2(sc[st][t][1] - m_new);
                float p2 = EXP2(sc[st][t][2] - m_new);
                float p3 = EXP2(sc[st][t][3] - m_new);
                rsumL += p0 + p1 + p2 + p3;
                pa[st][t] = (half4){(half_t)p0, (half_t)p1, (half_t)p2, (half_t)p3};
            }

            if (skip) {
                l_part[st] += rsumL;
            } else {
                float alpha = EXP2(m_i[st] - m_new);
                m_i[st] = m_new;
                l_part[st] = l_part[st] * alpha + rsumL;
                float ar[4];
                #pragma unroll
                for (int i = 0; i < 4; ++i) ar[i] = __shfl(alpha, quad * 4 + i);
                #pragma unroll
                for (int dt = 0; dt < 4; ++dt)
                    #pragma unroll
                    for (int i = 0; i < 4; ++i)
                        o[st][dt][i] *= ar[i];
            }
        }

        // O += P . V (bv frags shared: 1 read, 2 MFMAs)
        #pragma unroll
        for (int t = 0; t < 4; ++t) {
            #pragma unroll
            for (int dt = 0; dt < 4; ++dt) {
                half4 bv = *(const half4*)&Vts[(dt * 16 + col) * KPAD + t * 16 + quad * 4];
                #pragma unroll
                for (int st = 0; st < 2; ++st)
                    o[st][dt] = __builtin_amdgcn_mfma_f32_16x16x16f16(pa[st][t], bv, o[st][dt], 0, 0, 0);
            }
        }
    }

    // Epilogue: one cross-lane l reduction per strip; normalized partial O.
    const size_t pbase = (size_t)kz * HEAD_ELEMS + base;
    #pragma unroll
    for (int st = 0; st < 2; ++st) {
        float l_i = l_part[st] + __shfl_xor(l_part[st], 16);
        l_i += __shfl_xor(l_i, 32);
        float inv = 1.0f / l_i;
        float ir[4];
        #pragma unroll
        for (int i = 0; i < 4; ++i) ir[i] = __shfl(inv, quad * 4 + i);
        #pragma unroll
        for (int dt = 0; dt < 4; ++dt)
            #pragma unroll
            for (int i = 0; i < 4; ++i) {
                int row = q0 + wid * 32 + st * 16 + quad * 4 + i;
                pO[pbase + (size_t)row * DH + dt * 16 + col] = (half_t)(o[st][dt][i] * ir[i]);
            }
        if (quad == 0) {
            int row = q0 + wid * 32 + st * 16 + col;
            int idx = kz * NQROWS + bh * SS + row;
            mst[idx] = m_i[st];
            lst[idx] = l_i;
        }
    }
}

// ---------------------------------------------------------------------------
// merge: combine the four kz partials (m stats are log2-domain).
// 1024 blocks x 256 thr, 8 d-elems per thread (the twice-verified form;
// the 16-elem widening regressed in R16 and R18).
// ---------------------------------------------------------------------------
__global__ __launch_bounds__(256) void merge(const half_t* __restrict__ pO,
                                             const float* __restrict__ mst,
                                             const float* __restrict__ lst,
                                             float* __restrict__ out) {
    int gid = blockIdx.x * 256 + threadIdx.x;   // 0..262143
    int row = gid >> 3;                         // 0..32767 (bh*SS + s)
    int dc  = (gid & 7) * 8;
    float m[NKZ], l[NKZ];
    #pragma unroll
    for (int p = 0; p < NKZ; ++p) {
        m[p] = mst[p * NQROWS + row];
        l[p] = lst[p * NQROWS + row];
    }
    float M = fmaxf(fmaxf(m[0], m[1]), fmaxf(m[2], m[3]));
    float w[NKZ], wsum = 0.f;
    #pragma unroll
    for (int p = 0; p < NKZ; ++p) { w[p] = l[p] * EXP2(m[p] - M); wsum += w[p]; }
    float inv = 1.0f / wsum;

    float r[8] = {0.f,0.f,0.f,0.f,0.f,0.f,0.f,0.f};
    #pragma unroll
    for (int p = 0; p < NKZ; ++p) {
        float a = w[p] * inv;
        half8 ov = *(const half8*)&pO[(size_t)p * HEAD_ELEMS + (size_t)row * DH + dc];
        #pragma unroll
        for (int e = 0; e < 8; ++e) r[e] += a * (float)ov[e];
    }
    float4 r0 = {r[0], r[1], r[2], r[3]};
    float4 r1 = {r[4], r[5], r[6], r[7]};
    *(float4*)&out[(size_t)row * DH + dc]     = r0;
    *(float4*)&out[(size_t)row * DH + dc + 4] = r1;
}

extern "C" void kernel_launch(void* const* d_in, const int* in_sizes, int n_in,
                              void* d_out, int out_size, void* d_ws, size_t ws_size,
                              hipStream_t stream) {
    const float* x  = (const float*)d_in[0];   // [4,2048,256]
    const float* Wq = (const float*)d_in[1];   // [768,256]
    const float* bq = (const float*)d_in[2];   // [768]
    float* out = (float*)d_out;                // [4,4,2048,64]

    // ws layout (units of HEAD_ELEMS halfs; HE = 2M halfs = 4 MB):
    //   qh 0 | kh 1 | vt 2 | (3,4,5 free)
    //   pO 6..10 (4 kz partials, 16 MB) | stats f32 at byte 10*HE*2 (~42 MB)
    //   total ~43 MB; ws_size is 256 MiB.
    half_t* qh  = (half_t*)d_ws;
    half_t* kh  = qh + (size_t)HEAD_ELEMS;
    half_t* vt  = kh + (size_t)HEAD_ELEMS;
    half_t* pO  = (half_t*)d_ws + (size_t)6 * HEAD_ELEMS;  // 4 x HE halfs
    float*  mst = (float*)((char*)d_ws + (size_t)10 * HEAD_ELEMS * 2);
    float*  lst = mst + (size_t)NKZ * NQROWS;

    qkv_proj<<<dim3(NROW / 64, NE / 64), 256, 0, stream>>>(x, Wq, bq, qh, kh, vt);
    attn<<<dim3(SS / 128, BH, NKZ), 256, 0, stream>>>(qh, kh, vt, pO, mst, lst);
    merge<<<1024, 256, 0, stream>>>(pO, mst, lst, out);
}